// Round 1
// 192.199 us; speedup vs baseline: 1.1523x; 1.1523x over previous
//
#include <hip/hip_runtime.h>
#include <hip/hip_bf16.h>
#include <math.h>

// Fully-fused TCN, R10: async pipelined weight staging.
// - Weights staged via global_load_lds (16B) into double-buffered 32KB LDS
//   buffers; loads for tap t+1 issued right after barrier B(t), landing during
//   tap t's MFMAs. One __syncthreads per tap (its implicit vmcnt(0) drain is
//   the publish point). Barriers ~45 -> 22, staging VALU removed.
// - All LDS regions unpadded + XOR-swizzled at 16B granularity
//   (col ^= (row&7)<<3). Weight bank is pre-swizzled in prep_w so the linear
//   global_load_lds copy yields the swizzled LDS layout (both-sides rule).
// - LDS = 2x(192x128) activations + 2x(128x128) weights = 163840 B (160 KiB).

typedef __attribute__((ext_vector_type(8))) short short8;
typedef __attribute__((ext_vector_type(4))) short short4v;
typedef __attribute__((ext_vector_type(4))) float floatx4;

#define S_LEN 4096
#define ACT_STRIDE 128             // no pad; swizzle handles banks
#define ROWS 192                   // 64 halo + 128 outputs
#define AREG (ROWS * ACT_STRIDE)   // 24576 shorts per activation region
#define WBUF (128 * 128)           // 16384 shorts per weight buffer (32 KB)
#define LDS_BYTES ((2 * AREG + 2 * WBUF) * 2)   // 163840 B

// 16B-granular XOR swizzle (col in shorts, multiple of 4; never crosses unit)
#define SW(row, col) ((col) ^ (((row) & 7) << 3))

// weight bank offsets (shorts) — each tap contiguous, PRE-SWIZZLED layout
#define OFF_DS     0
#define OFF_L0C1_0 8192
#define OFF_L0C1_1 16384
#define OFF_L0C2_0 24576
#define OFF_L0C2_1 40960
#define OFF_C1B    57344      // + lvl*32768 ; tap1 at +16384
#define OFF_C2B    188416     // + lvl*32768 ; tap1 at +16384

__device__ __forceinline__ float elu_f(float v) {
    return v > 0.0f ? v : (__expf(v) - 1.0f);
}
__device__ __forceinline__ short f2bs(float v) {
    __hip_bfloat16 h = __float2bfloat16(v);
    return *reinterpret_cast<short*>(&h);
}
__device__ __forceinline__ float bs2f(short s) {
    __hip_bfloat16 h = *reinterpret_cast<__hip_bfloat16*>(&s);
    return __bfloat162float(h);
}
__device__ __forceinline__ short4v pack4(const floatx4 v) {
    __hip_bfloat162 p0 = __float22bfloat162_rn(make_float2(v[0], v[1]));
    __hip_bfloat162 p1 = __float22bfloat162_rn(make_float2(v[2], v[3]));
    short4v r;
    r[0] = ((const short*)&p0)[0]; r[1] = ((const short*)&p0)[1];
    r[2] = ((const short*)&p1)[0]; r[3] = ((const short*)&p1)[1];
    return r;
}

// async 16B global->LDS copy (wave-uniform LDS base + lane*16 hardware rule)
__device__ __forceinline__ void gld_lds16(const void* g, void* l) {
    __builtin_amdgcn_global_load_lds(
        (const __attribute__((address_space(1))) void*)g,
        (__attribute__((address_space(3))) void*)l, 16, 0, 0);
}

// Issue async loads of one pre-swizzled weight tap (NSH shorts) into LDS.
// 8 waves x NI insts x 1KB. Completion is published by the NEXT __syncthreads.
template<int NSH>
__device__ __forceinline__ void stage_async(short* __restrict__ lds,
                                            const short* __restrict__ src,
                                            int wave, int lane)
{
    constexpr int NI = (NSH * 2) / 8192;   // insts per wave (1 KB each)
    const char* g = (const char*)src + wave * 1024 + lane * 16;
    char* l = (char*)lds + wave * 1024;    // wave-uniform base
    #pragma unroll
    for (int i = 0; i < NI; ++i)
        gld_lds16(g + i * 8192, l + i * 8192);
}

// ---------------------------------------------------------------------------
// One tap's MFMAs: acc[mt][nt] += W[co][ci] * X[r - doff][ci].
// Both operand streams ds_read_b128 from swizzled LDS.
// ---------------------------------------------------------------------------
template<int KCH>
__device__ __forceinline__ void conv_tap(
    const short* __restrict__ Lin, const short* __restrict__ Lw,
    const int doff, const int srow, const int l16, const int quad,
    const int cobase, floatx4 (&acc)[4][3])
{
    #pragma unroll
    for (int kc = 0; kc < KCH; ++kc) {
        const int col  = kc * 32 + quad * 8;
        const int wcol = SW(l16, col);   // weight rows ≡ l16 (mod 8)
        short8 wf[4];
        #pragma unroll
        for (int mt = 0; mt < 4; ++mt)
            wf[mt] = *(const short8*)(Lw + (cobase + mt * 16 + l16) * (KCH * 32) + wcol);
        #pragma unroll
        for (int nt = 0; nt < 3; ++nt) {
            int r = srow + nt * 16 + l16 - doff;
            if (r < 0) r = 0;              // clamped rows never feed valid outputs
            const short8 bf = *(const short8*)(Lin + r * ACT_STRIDE + SW(r, col));
            #pragma unroll
            for (int mt = 0; mt < 4; ++mt)
                acc[mt][nt] = __builtin_amdgcn_mfma_f32_16x16x32_bf16(wf[mt], bf, acc[mt][nt], 0, 0, 0);
        }
    }
}

__device__ __forceinline__ void zero_acc(floatx4 (&acc)[4][3]) {
    #pragma unroll
    for (int mt = 0; mt < 4; ++mt)
        #pragma unroll
        for (int nt = 0; nt < 3; ++nt) acc[mt][nt] = {0.f, 0.f, 0.f, 0.f};
}

// ---------------------------------------------------------------------------
// Packed epilogue (swizzled addresses). MODE 0: elu(acc+b); 1: acc+b;
// 2: elu(elu(acc+b)+dst) in place (own-lane read+write).
// ---------------------------------------------------------------------------
template<int MODE, bool KEEP>
__device__ __forceinline__ void store_tile(short* __restrict__ dst,
    const floatx4 (&acc)[4][3], const float* __restrict__ bias,
    int cobase, int srow, int l16, int quad, int zero_below, short4v* keep)
{
    #pragma unroll
    for (int mt = 0; mt < 4; ++mt) {
        const int co4 = cobase + mt * 16 + quad * 4;
        const floatx4 bb = *(const floatx4*)(bias + co4);
        #pragma unroll
        for (int nt = 0; nt < 3; ++nt) {
            const int sl = srow + nt * 16 + l16;
            short* p = dst + sl * ACT_STRIDE + SW(sl, co4);
            floatx4 y;
            #pragma unroll
            for (int rr = 0; rr < 4; ++rr) {
                float v = acc[mt][nt][rr] + bb[rr];
                if (MODE != 1) v = elu_f(v);
                y[rr] = v;
            }
            if (MODE == 2) {
                const short4v old = *(const short4v*)p;
                #pragma unroll
                for (int rr = 0; rr < 4; ++rr) y[rr] = elu_f(y[rr] + bs2f(old[rr]));
            }
            if (sl < zero_below) y = {0.f, 0.f, 0.f, 0.f};
            const short4v pk = pack4(y);
            *(short4v*)p = pk;
            if (KEEP) keep[mt * 3 + nt] = pk;
        }
    }
}

// ---------------------------------------------------------------------------
__global__ __launch_bounds__(512, 2)
void tcn_fused(const float* __restrict__ x,     // fp32 [16,64,4096] channel-first
               const short* __restrict__ wq,
               const float* __restrict__ b1_0, const float* __restrict__ b2_0,
               const float* __restrict__ ds_b, const float* __restrict__ B1,
               const float* __restrict__ B2, float* __restrict__ out)
{
    extern __shared__ short L[];
    short* RA = L;                 // T buffer (also X staging, cols 0..63)
    short* RB = L + AREG;          // D buffer (residual chain)
    short* W0 = L + 2 * AREG;      // weight double-buffer
    short* W1 = L + 2 * AREG + WBUF;

    const int tid  = threadIdx.x;
    const int wave = tid >> 6, lane = tid & 63;
    const int l16  = lane & 15, quad = lane >> 4;
    const int cobase = (wave & 1) * 64;
    const int srow   = (wave >> 1) * 48;
    const int s0  = blockIdx.x * 128;
    const int s0g = s0 - 64;
    const int b   = blockIdx.y;
    const int zb  = (s0 == 0) ? 64 : 0;   // zero rows with global s < 0

    // ---- prologue: issue tap-0 (ds) weight loads, then stage X into RA
    stage_async<8192>(W0, wq + OFF_DS, wave, lane);
    {
        const float* xp = x + (size_t)b * 64 * S_LEN;
        #pragma unroll
        for (int h = 0; h < 3; ++h) {
            const int r = lane + h * 64;
            const int s = s0g + r;
            short8 pk;
            #pragma unroll
            for (int c8 = 0; c8 < 8; ++c8) {
                const float v = (s >= 0) ? xp[(wave * 8 + c8) * S_LEN + s] : 0.f;
                pk[c8] = f2bs(v);
            }
            *(short8*)(RA + r * ACT_STRIDE + SW(r, wave * 8)) = pk;
        }
    }

    floatx4 acc[4][3];
    short4v x1keep[12];

    // t0: ds (1x1, CIN=64): X(RA) -> D(RB)
    __syncthreads();                               // publishes X + ds weights
    stage_async<8192>(W1, wq + OFF_L0C1_0, wave, lane);
    zero_acc(acc);
    conv_tap<2>(RA, W0, 0, srow, l16, quad, cobase, acc);
    store_tile<1, false>(RB, acc, ds_b, cobase, srow, l16, quad, zb, nullptr);

    // t1: c1_0 k0 (d=1, CIN=64)
    __syncthreads();
    stage_async<8192>(W0, wq + OFF_L0C1_1, wave, lane);
    zero_acc(acc);
    conv_tap<2>(RA, W1, 1, srow, l16, quad, cobase, acc);

    // t2: c1_0 k1 -> T over RA (in-place: extra barrier before overwrite)
    __syncthreads();
    stage_async<16384>(W1, wq + OFF_L0C2_0, wave, lane);
    conv_tap<2>(RA, W0, 0, srow, l16, quad, cobase, acc);
    __syncthreads();                               // all X reads done
    store_tile<0, false>(RA, acc, b1_0, cobase, srow, l16, quad, zb, nullptr);

    // t3: c2_0 k0 (CIN=128)
    __syncthreads();
    stage_async<16384>(W0, wq + OFF_L0C2_1, wave, lane);
    zero_acc(acc);
    conv_tap<4>(RA, W1, 1, srow, l16, quad, cobase, acc);

    // t4: c2_0 k1 -> RB in place (res), keep x1
    __syncthreads();
    stage_async<16384>(W1, wq + OFF_C1B, wave, lane);
    conv_tap<4>(RA, W0, 0, srow, l16, quad, cobase, acc);
    store_tile<2, true>(RB, acc, b2_0, cobase, srow, l16, quad, zb, x1keep);

    // ---- levels 1..3 (d = 2, 4, 8)
    #pragma unroll
    for (int lvl = 0; lvl < 3; ++lvl) {
        const int d = 2 << lvl;
        const short* nc1k1 = wq + OFF_C1B + lvl * 32768 + 16384;
        const short* nc2k0 = wq + OFF_C2B + lvl * 32768;
        const short* nc2k1 = nc2k0 + 16384;
        const short* nnext = wq + OFF_C1B + (lvl + 1) * 32768;  // next level c1k0
        // c1 k0: RB -> acc              (uses W1, prefetch c1k1 -> W0)
        __syncthreads();
        stage_async<16384>(W0, nc1k1, wave, lane);
        zero_acc(acc);
        conv_tap<4>(RB, W1, d, srow, l16, quad, cobase, acc);
        // c1 k1: store T -> RA          (uses W0, prefetch c2k0 -> W1)
        __syncthreads();
        stage_async<16384>(W1, nc2k0, wave, lane);
        conv_tap<4>(RB, W0, 0, srow, l16, quad, cobase, acc);
        store_tile<0, false>(RA, acc, B1 + lvl * 128, cobase, srow, l16, quad, zb, nullptr);
        // c2 k0: RA -> acc              (uses W1, prefetch c2k1 -> W0)
        __syncthreads();
        stage_async<16384>(W0, nc2k1, wave, lane);
        zero_acc(acc);
        conv_tap<4>(RA, W1, d, srow, l16, quad, cobase, acc);
        // c2 k1: RB in place (res)      (uses W0, prefetch next c1k0 -> W1)
        __syncthreads();
        stage_async<16384>(W1, nnext, wave, lane);
        conv_tap<4>(RA, W0, 0, srow, l16, quad, cobase, acc);
        store_tile<2, false>(RB, acc, B2 + lvl * 128, cobase, srow, l16, quad, zb, nullptr);
    }

    // ---- level 4 (d=16)
    // t17: c1 k0 (uses W1, prefetch c1k1 -> W0)
    __syncthreads();
    stage_async<16384>(W0, wq + OFF_C1B + 3 * 32768 + 16384, wave, lane);
    zero_acc(acc);
    conv_tap<4>(RB, W1, 16, srow, l16, quad, cobase, acc);
    // t18: c1 k1 -> RA (uses W0, prefetch c2k0 -> W1)
    __syncthreads();
    stage_async<16384>(W1, wq + OFF_C2B + 3 * 32768, wave, lane);
    conv_tap<4>(RB, W0, 0, srow, l16, quad, cobase, acc);
    store_tile<0, false>(RA, acc, B1 + 384, cobase, srow, l16, quad, zb, nullptr);
    // t19: c2 k0 (uses W1, prefetch c2k1 -> W0)
    __syncthreads();
    stage_async<16384>(W0, wq + OFF_C2B + 3 * 32768 + 16384, wave, lane);
    zero_acc(acc);
    conv_tap<4>(RA, W1, 16, srow, l16, quad, cobase, acc);
    // t20: c2 k1 (uses W0) -> final epilogue, rows 64..191 only
    __syncthreads();
    conv_tap<4>(RA, W0, 0, srow, l16, quad, cobase, acc);
    {
        #pragma unroll
        for (int mt = 0; mt < 4; ++mt) {
            const int co4 = cobase + mt * 16 + quad * 4;
            const floatx4 bb = *(const floatx4*)(B2 + 384 + co4);
            #pragma unroll
            for (int nt = 0; nt < 3; ++nt) {
                if (srow + nt * 16 < 64) continue;     // halo rows: no output
                const int sl = srow + nt * 16 + l16;
                const int sg = s0g + sl;
                const short4v res = *(const short4v*)(RB + sl * ACT_STRIDE + SW(sl, co4));
                const short4v k   = x1keep[mt * 3 + nt];
                #pragma unroll
                for (int rr = 0; rr < 4; ++rr) {
                    float y = elu_f(acc[mt][nt][rr] + bb[rr]);
                    y = elu_f(y + bs2f(res[rr]));
                    y += bs2f(k[rr]);
                    out[((size_t)(b * 128 + co4 + rr)) * S_LEN + sg] = y;
                }
            }
        }
    }
}

// ---------------------------------------------------------------------------
// weights fp32 [co][ci][k] -> bf16 tap matrices [co][ci], PRE-SWIZZLED:
// logical (co,ci) stored at co*CIN + (ci ^ ((co&7)<<3)) so the linear
// global_load_lds copy produces the swizzled LDS layout the reads expect.
// ---------------------------------------------------------------------------
__global__ __launch_bounds__(256)
void prep_w(const float* __restrict__ w1_0, const float* __restrict__ w2_0,
            const float* __restrict__ ds_w, const float* __restrict__ W1,
            const float* __restrict__ W2, short* __restrict__ wq)
{
    int idx = blockIdx.x * 256 + threadIdx.x;
    const int n_c1 = 128 * 64;
    const int n_c2 = 128 * 128;
    if (idx < n_c1) {
        const int co = idx >> 6, ci = idx & 63;
        const int d = co * 64 + (ci ^ ((co & 7) << 3));
        wq[OFF_L0C1_0 + d] = f2bs(w1_0[idx * 2]);
        wq[OFF_L0C1_1 + d] = f2bs(w1_0[idx * 2 + 1]);
        return;
    }
    idx -= n_c1;
    if (idx < n_c2) {
        const int co = idx >> 7, ci = idx & 127;
        const int d = co * 128 + (ci ^ ((co & 7) << 3));
        wq[OFF_L0C2_0 + d] = f2bs(w2_0[idx * 2]);
        wq[OFF_L0C2_1 + d] = f2bs(w2_0[idx * 2 + 1]);
        return;
    }
    idx -= n_c2;
    if (idx < 4 * n_c2) {
        const int li = idx / n_c2, j = idx - li * n_c2;
        const int co = j >> 7, ci = j & 127;
        const int d = co * 128 + (ci ^ ((co & 7) << 3));
        wq[OFF_C1B + li * 32768 + d]         = f2bs(W1[(li * n_c2 + j) * 2]);
        wq[OFF_C1B + li * 32768 + 16384 + d] = f2bs(W1[(li * n_c2 + j) * 2 + 1]);
        return;
    }
    idx -= 4 * n_c2;
    if (idx < 4 * n_c2) {
        const int li = idx / n_c2, j = idx - li * n_c2;
        const int co = j >> 7, ci = j & 127;
        const int d = co * 128 + (ci ^ ((co & 7) << 3));
        wq[OFF_C2B + li * 32768 + d]         = f2bs(W2[(li * n_c2 + j) * 2]);
        wq[OFF_C2B + li * 32768 + 16384 + d] = f2bs(W2[(li * n_c2 + j) * 2 + 1]);
        return;
    }
    idx -= 4 * n_c2;
    if (idx < n_c1) {
        const int co = idx >> 6, ci = idx & 63;
        const int d = co * 64 + (ci ^ ((co & 7) << 3));
        wq[OFF_DS + d] = f2bs(ds_w[idx]);
    }
}

// ---------------------------------------------------------------------------
extern "C" void kernel_launch(void* const* d_in, const int* in_sizes, int n_in,
                              void* d_out, int out_size, void* d_ws, size_t ws_size,
                              hipStream_t stream) {
    const float* x_in = (const float*)d_in[0];
    const float* w1_0 = (const float*)d_in[1];
    const float* b1_0 = (const float*)d_in[2];
    const float* w2_0 = (const float*)d_in[3];
    const float* b2_0 = (const float*)d_in[4];
    const float* ds_w = (const float*)d_in[5];
    const float* ds_b = (const float*)d_in[6];
    const float* W1   = (const float*)d_in[7];
    const float* B1   = (const float*)d_in[8];
    const float* W2   = (const float*)d_in[9];
    const float* B2   = (const float*)d_in[10];
    float* out = (float*)d_out;

    short* wq = (short*)d_ws;   // 624 KB pre-swizzled weight bank

    (void)hipFuncSetAttribute((const void*)tcn_fused,
                              hipFuncAttributeMaxDynamicSharedMemorySize, LDS_BYTES);

    prep_w<<<dim3(640), 256, 0, stream>>>(w1_0, w2_0, ds_w, W1, W2, wq);
    tcn_fused<<<dim3(32, 16), dim3(512), LDS_BYTES, stream>>>(
        x_in, wq, b1_0, b2_0, ds_b, B1, B2, out);
}

// Round 2
// 183.367 us; speedup vs baseline: 1.2078x; 1.0482x over previous
//
#include <hip/hip_runtime.h>
#include <hip/hip_bf16.h>
#include <math.h>

// Fully-fused TCN, R11: 1024 threads / 16 waves (4 waves per SIMD).
// R10 analysis: nothing saturated (MFMA 6%, LDS pipe ~37%, VALU 38%, HBM 5%)
// -> latency-bound at 2 waves/SIMD (160KB LDS = 1 block/CU). This round keeps
// the async weight pipeline + 16B XOR swizzle and doubles wave concurrency:
// wave tile 32co x 48rows (mt=2, nt=3), 4 co-groups x 4 row-groups.
// LDS = 2x(192x128) activations + 2x(128x128) weights = 163840 B (160 KiB).

typedef __attribute__((ext_vector_type(8))) short short8;
typedef __attribute__((ext_vector_type(4))) short short4v;
typedef __attribute__((ext_vector_type(4))) float floatx4;

#define S_LEN 4096
#define ACT_STRIDE 128             // no pad; swizzle handles banks
#define ROWS 192                   // 64 halo + 128 outputs
#define AREG (ROWS * ACT_STRIDE)   // 24576 shorts per activation region
#define WBUF (128 * 128)           // 16384 shorts per weight buffer (32 KB)
#define LDS_BYTES ((2 * AREG + 2 * WBUF) * 2)   // 163840 B

// 16B-granular XOR swizzle (col in shorts; swizzle flips short-bits 3..5)
#define SW(row, col) ((col) ^ (((row) & 7) << 3))

// weight bank offsets (shorts) — each tap contiguous, PRE-SWIZZLED layout
#define OFF_DS     0
#define OFF_L0C1_0 8192
#define OFF_L0C1_1 16384
#define OFF_L0C2_0 24576
#define OFF_L0C2_1 40960
#define OFF_C1B    57344      // + lvl*32768 ; tap1 at +16384
#define OFF_C2B    188416     // + lvl*32768 ; tap1 at +16384

__device__ __forceinline__ float elu_f(float v) {
    return v > 0.0f ? v : (__expf(v) - 1.0f);
}
__device__ __forceinline__ short f2bs(float v) {
    __hip_bfloat16 h = __float2bfloat16(v);
    return *reinterpret_cast<short*>(&h);
}
__device__ __forceinline__ float bs2f(short s) {
    __hip_bfloat16 h = *reinterpret_cast<__hip_bfloat16*>(&s);
    return __bfloat162float(h);
}
__device__ __forceinline__ short4v pack4(const floatx4 v) {
    __hip_bfloat162 p0 = __float22bfloat162_rn(make_float2(v[0], v[1]));
    __hip_bfloat162 p1 = __float22bfloat162_rn(make_float2(v[2], v[3]));
    short4v r;
    r[0] = ((const short*)&p0)[0]; r[1] = ((const short*)&p0)[1];
    r[2] = ((const short*)&p1)[0]; r[3] = ((const short*)&p1)[1];
    return r;
}

// async 16B global->LDS copy (wave-uniform LDS base + lane*16 hardware rule)
__device__ __forceinline__ void gld_lds16(const void* g, void* l) {
    __builtin_amdgcn_global_load_lds(
        (const __attribute__((address_space(1))) void*)g,
        (__attribute__((address_space(3))) void*)l, 16, 0, 0);
}

// Issue async loads of one pre-swizzled weight tap (NSH shorts) into LDS.
// 16 waves x NI insts x 1KB. Completion is published by the NEXT __syncthreads.
template<int NSH>
__device__ __forceinline__ void stage_async(short* __restrict__ lds,
                                            const short* __restrict__ src,
                                            int wave, int lane)
{
    constexpr int NI = (NSH * 2) / 16384;  // insts per wave (1 KB each, 16 waves)
    const char* g = (const char*)src + wave * 1024 + lane * 16;
    char* l = (char*)lds + wave * 1024;    // wave-uniform base
    #pragma unroll
    for (int i = 0; i < NI; ++i)
        gld_lds16(g + i * 16384, l + i * 16384);
}

// ---------------------------------------------------------------------------
// One tap's MFMAs: acc[mt][nt] += W[co][ci] * X[r - doff][ci].
// Both operand streams ds_read_b128 from swizzled LDS. Wave tile 32co x 48row.
// ---------------------------------------------------------------------------
template<int KCH>
__device__ __forceinline__ void conv_tap(
    const short* __restrict__ Lin, const short* __restrict__ Lw,
    const int doff, const int srow, const int l16, const int quad,
    const int cobase, floatx4 (&acc)[2][3])
{
    #pragma unroll
    for (int kc = 0; kc < KCH; ++kc) {
        const int col  = kc * 32 + quad * 8;
        const int wcol = SW(l16, col);   // weight rows ≡ l16 (mod 8)
        short8 wf[2];
        #pragma unroll
        for (int mt = 0; mt < 2; ++mt)
            wf[mt] = *(const short8*)(Lw + (cobase + mt * 16 + l16) * (KCH * 32) + wcol);
        #pragma unroll
        for (int nt = 0; nt < 3; ++nt) {
            int r = srow + nt * 16 + l16 - doff;
            if (r < 0) r = 0;              // clamped rows never feed valid outputs
            const short8 bf = *(const short8*)(Lin + r * ACT_STRIDE + SW(r, col));
            #pragma unroll
            for (int mt = 0; mt < 2; ++mt)
                acc[mt][nt] = __builtin_amdgcn_mfma_f32_16x16x32_bf16(wf[mt], bf, acc[mt][nt], 0, 0, 0);
        }
    }
}

__device__ __forceinline__ void zero_acc(floatx4 (&acc)[2][3]) {
    #pragma unroll
    for (int mt = 0; mt < 2; ++mt)
        #pragma unroll
        for (int nt = 0; nt < 3; ++nt) acc[mt][nt] = {0.f, 0.f, 0.f, 0.f};
}

// ---------------------------------------------------------------------------
// Packed epilogue (swizzled addresses). MODE 0: elu(acc+b); 1: acc+b;
// 2: elu(elu(acc+b)+dst) in place (own-lane read+write).
// ---------------------------------------------------------------------------
template<int MODE, bool KEEP>
__device__ __forceinline__ void store_tile(short* __restrict__ dst,
    const floatx4 (&acc)[2][3], const float* __restrict__ bias,
    int cobase, int srow, int l16, int quad, int zero_below, short4v* keep)
{
    #pragma unroll
    for (int mt = 0; mt < 2; ++mt) {
        const int co4 = cobase + mt * 16 + quad * 4;
        const floatx4 bb = *(const floatx4*)(bias + co4);
        #pragma unroll
        for (int nt = 0; nt < 3; ++nt) {
            const int sl = srow + nt * 16 + l16;
            short* p = dst + sl * ACT_STRIDE + SW(sl, co4);
            floatx4 y;
            #pragma unroll
            for (int rr = 0; rr < 4; ++rr) {
                float v = acc[mt][nt][rr] + bb[rr];
                if (MODE != 1) v = elu_f(v);
                y[rr] = v;
            }
            if (MODE == 2) {
                const short4v old = *(const short4v*)p;
                #pragma unroll
                for (int rr = 0; rr < 4; ++rr) y[rr] = elu_f(y[rr] + bs2f(old[rr]));
            }
            if (sl < zero_below) y = {0.f, 0.f, 0.f, 0.f};
            const short4v pk = pack4(y);
            *(short4v*)p = pk;
            if (KEEP) keep[mt * 3 + nt] = pk;
        }
    }
}

// ---------------------------------------------------------------------------
__global__ __launch_bounds__(1024, 4)
void tcn_fused(const float* __restrict__ x,     // fp32 [16,64,4096] channel-first
               const short* __restrict__ wq,
               const float* __restrict__ b1_0, const float* __restrict__ b2_0,
               const float* __restrict__ ds_b, const float* __restrict__ B1,
               const float* __restrict__ B2, float* __restrict__ out)
{
    extern __shared__ short L[];
    short* RA = L;                 // T buffer (also X staging)
    short* RB = L + AREG;          // D buffer (residual chain)
    short* W0 = L + 2 * AREG;      // weight double-buffer
    short* W1 = L + 2 * AREG + WBUF;

    const int tid  = threadIdx.x;
    const int wave = tid >> 6, lane = tid & 63;
    const int l16  = lane & 15, quad = lane >> 4;
    const int cobase = (wave & 3) * 32;    // 4 co-groups of 32
    const int srow   = (wave >> 2) * 48;   // 4 row-groups of 48
    const int s0  = blockIdx.x * 128;
    const int s0g = s0 - 64;
    const int b   = blockIdx.y;
    const int zb  = (s0 == 0) ? 64 : 0;   // zero rows with global s < 0

    // ---- prologue: issue tap-0 (ds) weight loads, then stage X into RA
    stage_async<8192>(W0, wq + OFF_DS, wave, lane);
    {
        const float* xp = x + (size_t)b * 64 * S_LEN;
        #pragma unroll
        for (int h = 0; h < 3; ++h) {
            const int r = lane + h * 64;
            const int s = s0g + r;
            short4v pk;
            #pragma unroll
            for (int c4 = 0; c4 < 4; ++c4) {
                const float v = (s >= 0) ? xp[(wave * 4 + c4) * S_LEN + s] : 0.f;
                pk[c4] = f2bs(v);
            }
            *(short4v*)(RA + r * ACT_STRIDE + SW(r, wave * 4)) = pk;
        }
    }

    floatx4 acc[2][3];
    short4v x1keep[6];

    // t0: ds (1x1, CIN=64): X(RA) -> D(RB)
    __syncthreads();                               // publishes X + ds weights
    stage_async<8192>(W1, wq + OFF_L0C1_0, wave, lane);
    zero_acc(acc);
    conv_tap<2>(RA, W0, 0, srow, l16, quad, cobase, acc);
    store_tile<1, false>(RB, acc, ds_b, cobase, srow, l16, quad, zb, nullptr);

    // t1: c1_0 k0 (d=1, CIN=64)
    __syncthreads();
    stage_async<8192>(W0, wq + OFF_L0C1_1, wave, lane);
    zero_acc(acc);
    conv_tap<2>(RA, W1, 1, srow, l16, quad, cobase, acc);

    // t2: c1_0 k1 -> T over RA (in-place: extra barrier before overwrite)
    __syncthreads();
    stage_async<16384>(W1, wq + OFF_L0C2_0, wave, lane);
    conv_tap<2>(RA, W0, 0, srow, l16, quad, cobase, acc);
    __syncthreads();                               // all X reads done
    store_tile<0, false>(RA, acc, b1_0, cobase, srow, l16, quad, zb, nullptr);

    // t3: c2_0 k0 (CIN=128)
    __syncthreads();
    stage_async<16384>(W0, wq + OFF_L0C2_1, wave, lane);
    zero_acc(acc);
    conv_tap<4>(RA, W1, 1, srow, l16, quad, cobase, acc);

    // t4: c2_0 k1 -> RB in place (res), keep x1
    __syncthreads();
    stage_async<16384>(W1, wq + OFF_C1B, wave, lane);
    conv_tap<4>(RA, W0, 0, srow, l16, quad, cobase, acc);
    store_tile<2, true>(RB, acc, b2_0, cobase, srow, l16, quad, zb, x1keep);

    // ---- levels 1..3 (d = 2, 4, 8)
    #pragma unroll
    for (int lvl = 0; lvl < 3; ++lvl) {
        const int d = 2 << lvl;
        const short* nc1k1 = wq + OFF_C1B + lvl * 32768 + 16384;
        const short* nc2k0 = wq + OFF_C2B + lvl * 32768;
        const short* nc2k1 = nc2k0 + 16384;
        const short* nnext = wq + OFF_C1B + (lvl + 1) * 32768;  // next level c1k0
        // c1 k0: RB -> acc              (uses W1, prefetch c1k1 -> W0)
        __syncthreads();
        stage_async<16384>(W0, nc1k1, wave, lane);
        zero_acc(acc);
        conv_tap<4>(RB, W1, d, srow, l16, quad, cobase, acc);
        // c1 k1: store T -> RA          (uses W0, prefetch c2k0 -> W1)
        __syncthreads();
        stage_async<16384>(W1, nc2k0, wave, lane);
        conv_tap<4>(RB, W0, 0, srow, l16, quad, cobase, acc);
        store_tile<0, false>(RA, acc, B1 + lvl * 128, cobase, srow, l16, quad, zb, nullptr);
        // c2 k0: RA -> acc              (uses W1, prefetch c2k1 -> W0)
        __syncthreads();
        stage_async<16384>(W0, nc2k1, wave, lane);
        zero_acc(acc);
        conv_tap<4>(RA, W1, d, srow, l16, quad, cobase, acc);
        // c2 k1: RB in place (res)      (uses W0, prefetch next c1k0 -> W1)
        __syncthreads();
        stage_async<16384>(W1, nnext, wave, lane);
        conv_tap<4>(RA, W0, 0, srow, l16, quad, cobase, acc);
        store_tile<2, false>(RB, acc, B2 + lvl * 128, cobase, srow, l16, quad, zb, nullptr);
    }

    // ---- level 4 (d=16)
    // t17: c1 k0 (uses W1, prefetch c1k1 -> W0)
    __syncthreads();
    stage_async<16384>(W0, wq + OFF_C1B + 3 * 32768 + 16384, wave, lane);
    zero_acc(acc);
    conv_tap<4>(RB, W1, 16, srow, l16, quad, cobase, acc);
    // t18: c1 k1 -> RA (uses W0, prefetch c2k0 -> W1)
    __syncthreads();
    stage_async<16384>(W1, wq + OFF_C2B + 3 * 32768, wave, lane);
    conv_tap<4>(RB, W0, 0, srow, l16, quad, cobase, acc);
    store_tile<0, false>(RA, acc, B1 + 384, cobase, srow, l16, quad, zb, nullptr);
    // t19: c2 k0 (uses W1, prefetch c2k1 -> W0)
    __syncthreads();
    stage_async<16384>(W0, wq + OFF_C2B + 3 * 32768 + 16384, wave, lane);
    zero_acc(acc);
    conv_tap<4>(RA, W1, 16, srow, l16, quad, cobase, acc);
    // t20: c2 k1 (uses W0) -> final epilogue, rows 64..191 only
    __syncthreads();
    conv_tap<4>(RA, W0, 0, srow, l16, quad, cobase, acc);
    {
        #pragma unroll
        for (int mt = 0; mt < 2; ++mt) {
            const int co4 = cobase + mt * 16 + quad * 4;
            const floatx4 bb = *(const floatx4*)(B2 + 384 + co4);
            #pragma unroll
            for (int nt = 0; nt < 3; ++nt) {
                if (srow + nt * 16 < 64) continue;     // halo rows: no output
                const int sl = srow + nt * 16 + l16;
                const int sg = s0g + sl;
                const short4v res = *(const short4v*)(RB + sl * ACT_STRIDE + SW(sl, co4));
                const short4v k   = x1keep[mt * 3 + nt];
                #pragma unroll
                for (int rr = 0; rr < 4; ++rr) {
                    float y = elu_f(acc[mt][nt][rr] + bb[rr]);
                    y = elu_f(y + bs2f(res[rr]));
                    y += bs2f(k[rr]);
                    out[((size_t)(b * 128 + co4 + rr)) * S_LEN + sg] = y;
                }
            }
        }
    }
}

// ---------------------------------------------------------------------------
// weights fp32 [co][ci][k] -> bf16 tap matrices [co][ci], PRE-SWIZZLED:
// logical (co,ci) stored at co*CIN + (ci ^ ((co&7)<<3)) so the linear
// global_load_lds copy produces the swizzled LDS layout the reads expect.
// ---------------------------------------------------------------------------
__global__ __launch_bounds__(256)
void prep_w(const float* __restrict__ w1_0, const float* __restrict__ w2_0,
            const float* __restrict__ ds_w, const float* __restrict__ W1,
            const float* __restrict__ W2, short* __restrict__ wq)
{
    int idx = blockIdx.x * 256 + threadIdx.x;
    const int n_c1 = 128 * 64;
    const int n_c2 = 128 * 128;
    if (idx < n_c1) {
        const int co = idx >> 6, ci = idx & 63;
        const int d = co * 64 + (ci ^ ((co & 7) << 3));
        wq[OFF_L0C1_0 + d] = f2bs(w1_0[idx * 2]);
        wq[OFF_L0C1_1 + d] = f2bs(w1_0[idx * 2 + 1]);
        return;
    }
    idx -= n_c1;
    if (idx < n_c2) {
        const int co = idx >> 7, ci = idx & 127;
        const int d = co * 128 + (ci ^ ((co & 7) << 3));
        wq[OFF_L0C2_0 + d] = f2bs(w2_0[idx * 2]);
        wq[OFF_L0C2_1 + d] = f2bs(w2_0[idx * 2 + 1]);
        return;
    }
    idx -= n_c2;
    if (idx < 4 * n_c2) {
        const int li = idx / n_c2, j = idx - li * n_c2;
        const int co = j >> 7, ci = j & 127;
        const int d = co * 128 + (ci ^ ((co & 7) << 3));
        wq[OFF_C1B + li * 32768 + d]         = f2bs(W1[(li * n_c2 + j) * 2]);
        wq[OFF_C1B + li * 32768 + 16384 + d] = f2bs(W1[(li * n_c2 + j) * 2 + 1]);
        return;
    }
    idx -= 4 * n_c2;
    if (idx < 4 * n_c2) {
        const int li = idx / n_c2, j = idx - li * n_c2;
        const int co = j >> 7, ci = j & 127;
        const int d = co * 128 + (ci ^ ((co & 7) << 3));
        wq[OFF_C2B + li * 32768 + d]         = f2bs(W2[(li * n_c2 + j) * 2]);
        wq[OFF_C2B + li * 32768 + 16384 + d] = f2bs(W2[(li * n_c2 + j) * 2 + 1]);
        return;
    }
    idx -= 4 * n_c2;
    if (idx < n_c1) {
        const int co = idx >> 6, ci = idx & 63;
        const int d = co * 64 + (ci ^ ((co & 7) << 3));
        wq[OFF_DS + d] = f2bs(ds_w[idx]);
    }
}

// ---------------------------------------------------------------------------
extern "C" void kernel_launch(void* const* d_in, const int* in_sizes, int n_in,
                              void* d_out, int out_size, void* d_ws, size_t ws_size,
                              hipStream_t stream) {
    const float* x_in = (const float*)d_in[0];
    const float* w1_0 = (const float*)d_in[1];
    const float* b1_0 = (const float*)d_in[2];
    const float* w2_0 = (const float*)d_in[3];
    const float* b2_0 = (const float*)d_in[4];
    const float* ds_w = (const float*)d_in[5];
    const float* ds_b = (const float*)d_in[6];
    const float* W1   = (const float*)d_in[7];
    const float* B1   = (const float*)d_in[8];
    const float* W2   = (const float*)d_in[9];
    const float* B2   = (const float*)d_in[10];
    float* out = (float*)d_out;

    short* wq = (short*)d_ws;   // 624 KB pre-swizzled weight bank

    (void)hipFuncSetAttribute((const void*)tcn_fused,
                              hipFuncAttributeMaxDynamicSharedMemorySize, LDS_BYTES);

    prep_w<<<dim3(640), 256, 0, stream>>>(w1_0, w2_0, ds_w, W1, W2, wq);
    tcn_fused<<<dim3(32, 16), dim3(1024), LDS_BYTES, stream>>>(
        x_in, wq, b1_0, b2_0, ds_b, B1, B2, out);
}